// Round 14
// baseline (2859.876 us; speedup 1.0000x reference)
//
#include <hip/hip_runtime.h>

__device__ __forceinline__ float lrelu(float x) { return x >= 0.f ? x : 0.2f * x; }

typedef const __attribute__((address_space(1))) void* gas_ptr;
typedef __attribute__((address_space(3))) void* las_ptr;

// ---------------------------------------------------------------------------
// conv0: fp32 x (4,3,256,256) (half batch), w (64,3,3,3), s1 p1, +bias+lrelu
// -> ACTIVATED fp32 PADDED h0p (4,64,258,260), interior at (1,1)
// ---------------------------------------------------------------------------
__global__ __launch_bounds__(256) void conv0_k(const float* __restrict__ x,
                                               const float* __restrict__ w,
                                               const float* __restrict__ bias,
                                               float* __restrict__ out) {
    __shared__ float sIn[3][34][34];
    __shared__ float sW[27][16];
    const int H = 256;
    int tid = threadIdx.x, tx = tid & 31, ty = tid >> 5;
    int tX = (blockIdx.x & 7) * 32, tY = (blockIdx.x >> 3) * 32;
    int b = blockIdx.y, cog = blockIdx.z * 16;
    float acc[4][16] = {};
    const float* inB = x + (size_t)b * 3 * H * H;
    for (int idx = tid; idx < 3 * 1156; idx += 256) {
        int ci = idx / 1156, r = idx % 1156, iy = r / 34, ix = r % 34;
        int gy = tY - 1 + iy, gx = tX - 1 + ix;
        float v = 0.f;
        if ((unsigned)gy < 256u && (unsigned)gx < 256u)
            v = inB[(ci * H + gy) * H + gx];
        sIn[ci][iy][ix] = v;
    }
    for (int idx = tid; idx < 27 * 16; idx += 256) {
        int co = idx & 15, rest = idx >> 4;
        sW[rest][co] = w[(cog + co) * 27 + rest];
    }
    __syncthreads();
#pragma unroll
    for (int ci = 0; ci < 3; ci++)
#pragma unroll
        for (int dy = 0; dy < 3; dy++)
#pragma unroll
            for (int dx = 0; dx < 3; dx++) {
                float a0 = sIn[ci][ty + dy][tx + dx];
                float a1 = sIn[ci][ty + 8 + dy][tx + dx];
                float a2 = sIn[ci][ty + 16 + dy][tx + dx];
                float a3 = sIn[ci][ty + 24 + dy][tx + dx];
                const float* wp = sW[ci * 9 + dy * 3 + dx];
#pragma unroll
                for (int co = 0; co < 16; co++) {
                    float wv = wp[co];
                    acc[0][co] += a0 * wv; acc[1][co] += a1 * wv;
                    acc[2][co] += a2 * wv; acc[3][co] += a3 * wv;
                }
            }
    float* outB = out + (size_t)(b * 64 + cog) * 67080;   // 258*260
#pragma unroll
    for (int co = 0; co < 16; co++) {
        float bv = bias[cog + co];
#pragma unroll
        for (int r = 0; r < 4; r++)
            outB[(size_t)co * 67080 + (size_t)(tY + ty + 8 * r + 1) * 260 +
                 tX + tx + 1] = lrelu(acc[r][co] + bv);
    }
}

// ---------------------------------------------------------------------------
// Wave-shuffle BN-stats epilogue: per-thread 2 values -> wave reduce (6
// shfl) -> tiny LDS -> per-channel double2 partial. Needs sRedS/Q[4*COG].
// ---------------------------------------------------------------------------
template <int COG>
__device__ __forceinline__ void stats_epi(float (&acc)[2][COG],
                                          float* sRedS, float* sRedQ,
                                          double2* part, int cog,
                                          int slotBase, int S, int tid) {
    const int wv = tid >> 6, l = tid & 63;
#pragma unroll
    for (int c = 0; c < COG; c++) {
        float s = acc[0][c] + acc[1][c];
        float q = acc[0][c] * acc[0][c] + acc[1][c] * acc[1][c];
#pragma unroll
        for (int off = 32; off > 0; off >>= 1) {
            s += __shfl_xor(s, off);
            q += __shfl_xor(q, off);
        }
        if (l == 0) { sRedS[wv * COG + c] = s; sRedQ[wv * COG + c] = q; }
    }
    __syncthreads();
    if (tid < COG) {
        float s = sRedS[tid] + sRedS[COG + tid] + sRedS[2 * COG + tid] +
                  sRedS[3 * COG + tid];
        float q = sRedQ[tid] + sRedQ[COG + tid] + sRedQ[2 * COG + tid] +
                  sRedQ[3 * COG + tid];
        int slot = slotBase + blockIdx.y * gridDim.x + blockIdx.x;
        part[(size_t)(cog + tid) * S + slot].x = (double)s;
        part[(size_t)(cog + tid) * S + slot].y = (double)q;
    }
}

// ---------------------------------------------------------------------------
// Async padded 4x4 s2 conv (conv1, conv3), 32x16-out tiles (2 rows/thread).
// Input ACTIVATED padded (Hp,Wp), interior (1,1), borders zero. Pure
// global_load_lds staging (R11-proven LDS-linear pattern). Fused stats.
// ---------------------------------------------------------------------------
template <int COG>
__global__ __launch_bounds__(256) void c4x4p_k(const float* __restrict__ in,
                                               const float* __restrict__ w,
                                               float* __restrict__ out,
                                               double2* __restrict__ part,
                                               int slotBase, int S,
                                               int Cin, int Cout, int Hin,
                                               int Hp, int Wp,
                                               int oHp, int oWp, int oOff) {
    __shared__ float sIn[2][2312];            // 34 rows x 68 cols
    __shared__ float sW[2][16 * COG];
    __shared__ float sRedS[4 * COG], sRedQ[4 * COG];
    const int Hout = Hin >> 1;
    const int tid = threadIdx.x, tx = tid & 31, ty = tid >> 5;
    const int tpr = Hout >> 5;
    const int tX = (blockIdx.x % tpr) * 32, tY = (blockIdx.x / tpr) * 16;
    const int b = blockIdx.y, cog = blockIdx.z * COG;
    const int HWin = Hp * Wp;
    const float* inB = in + (size_t)b * Cin * HWin;
    const int wvbase = tid & ~63;

    int gOff[3]; int lOff[3]; bool act[3];
#pragma unroll
    for (int r = 0; r < 3; r++) {
        int idx = tid + r * 256;
        bool a = idx < 578;                   // 34 rows x 17 float4
        int row = idx / 17, c4 = idx % 17;
        gOff[r] = a ? ((2 * tY + row) * Wp + 2 * tX + 4 * c4) : 0;
        lOff[r] = (r * 256 + wvbase) * 4;
        act[r] = a;
    }
    const int wco = tid % COG, wt = tid / COG;
    const int wgo = ((cog + wco) * Cin) * 16 + wt;
    const bool wact = tid < 16 * COG;

    float acc[2][COG];
#pragma unroll
    for (int j = 0; j < 2; j++)
#pragma unroll
        for (int c = 0; c < COG; c++) acc[j][c] = 0.f;

#pragma unroll
    for (int r = 0; r < 3; r++)
        if (act[r])
            __builtin_amdgcn_global_load_lds((gas_ptr)(inB + gOff[r]),
                                             (las_ptr)(&sIn[0][lOff[r]]), 16, 0, 0);
    if (wact)
        __builtin_amdgcn_global_load_lds((gas_ptr)(w + wgo),
                                         (las_ptr)(&sW[0][wvbase]), 4, 0, 0);
    __syncthreads();

    for (int k = 0; k < Cin; k++) {
        const int cur = k & 1, nb = cur ^ 1;
        const bool more = (k + 1) < Cin;
        if (more) {
            const float* p = inB + (size_t)(k + 1) * HWin;
#pragma unroll
            for (int r = 0; r < 3; r++)
                if (act[r])
                    __builtin_amdgcn_global_load_lds(
                        (gas_ptr)(p + gOff[r]),
                        (las_ptr)(&sIn[nb][lOff[r]]), 16, 0, 0);
            if (wact)
                __builtin_amdgcn_global_load_lds(
                    (gas_ptr)(w + wgo + (k + 1) * 16),
                    (las_ptr)(&sW[nb][wvbase]), 4, 0, 0);
        }
        const float* sI = sIn[cur];
        const float* sw = sW[cur];
#pragma unroll
        for (int dy = 0; dy < 4; dy++)
#pragma unroll
            for (int dx = 0; dx < 4; dx++) {
                const float* bp = sI + (4 * ty + dy) * 68 + 2 * tx + dx;
                float a0 = bp[0];
                float a1 = bp[2 * 68];
                const float* wp = sw + (dy * 4 + dx) * COG;
#pragma unroll
                for (int c = 0; c < COG; c++) {
                    float wv = wp[c];
                    acc[0][c] += a0 * wv; acc[1][c] += a1 * wv;
                }
            }
        __syncthreads();
    }

    float* outB = out + (size_t)(b * Cout + cog) * oHp * oWp;
#pragma unroll
    for (int c = 0; c < COG; c++)
#pragma unroll
        for (int j = 0; j < 2; j++)
            outB[(size_t)c * oHp * oWp +
                 (size_t)(tY + 2 * ty + j + oOff) * oWp + tX + tx + oOff] =
                acc[j][c];
    stats_epi<COG>(acc, sRedS, sRedQ, part, cog, slotBase, S, tid);
}

// ---------------------------------------------------------------------------
// Async padded 3x3 s1 conv, 32x16-out tiles (2 rows/thread), 4-row register
// reuse, double-buffered LDS, global_load_lds staging, fused stats.
// VGPR notes: R8 (cap 64 -> spill) and R10 (COG16, 2 waves/SIMD) regressed;
// COG=8 async small-tile aims at 8 blocks/CU.
// ---------------------------------------------------------------------------
template <int COG>
__global__ __launch_bounds__(256) void c3x3_k(const float* __restrict__ in,
                                              const float* __restrict__ w,
                                              float* __restrict__ out,
                                              double2* __restrict__ part,
                                              int slotBase, int S,
                                              int Cin, int Cout, int H,
                                              int Hp, int Wp,
                                              int oHp, int oWp, int oOff) {
    constexpr int RS = 36;
    constexpr int CI = 18 * RS;               // 648
    __shared__ float sIn[2][2 * CI];
    __shared__ float sW[2][18 * COG];
    __shared__ float sRedS[4 * COG], sRedQ[4 * COG];
    const int tid = threadIdx.x, tx = tid & 31, ty = tid >> 5;
    const int tpr = H >> 5;
    const int tX = (blockIdx.x % tpr) * 32, tY = (blockIdx.x / tpr) * 16;
    const int b = blockIdx.y, cog = blockIdx.z * COG;
    const int HWin = Hp * Wp;
    const float* inB = in + (size_t)b * Cin * HWin;
    const int wvbase = tid & ~63;

    int gOff[2]; int lOff[2]; bool act[2];
#pragma unroll
    for (int r = 0; r < 2; r++) {
        int idx = tid + r * 256;
        bool a = idx < 324;                   // 2 cins x 18 rows x 9 float4
        int ci = idx / 162, rem = idx % 162;
        int row = rem / 9, c4 = rem % 9;
        gOff[r] = a ? (ci * HWin + (tY + row) * Wp + tX + 4 * c4) : 0;
        lOff[r] = (r * 256 + wvbase) * 4;
        act[r] = a;
    }
    constexpr int NW = (18 * COG + 255) / 256;
    int wgo[NW]; bool wact[NW];
#pragma unroll
    for (int r = 0; r < NW; r++) {
        int widx = tid + r * 256;
        bool a = widx < 18 * COG;
        int co = widx % COG, rest = widx / COG;
        int ci = rest / 9, t = rest % 9;
        wgo[r] = a ? (((cog + co) * Cin + ci) * 9 + t) : 0;
        wact[r] = a;
    }

    float acc[2][COG];
#pragma unroll
    for (int j = 0; j < 2; j++)
#pragma unroll
        for (int c = 0; c < COG; c++) acc[j][c] = 0.f;

    const int steps = Cin >> 1;

#pragma unroll
    for (int r = 0; r < 2; r++)
        if (act[r])
            __builtin_amdgcn_global_load_lds(
                (gas_ptr)(inB + gOff[r]),
                (las_ptr)(&sIn[0][lOff[r]]), 16, 0, 0);
#pragma unroll
    for (int r = 0; r < NW; r++)
        if (wact[r])
            __builtin_amdgcn_global_load_lds(
                (gas_ptr)(w + wgo[r]),
                (las_ptr)(&sW[0][r * 256 + wvbase]), 4, 0, 0);
    __syncthreads();

    for (int k = 0; k < steps; k++) {
        const int cur = k & 1;
        const int nb = cur ^ 1;
        const bool more = (k + 1) < steps;
        if (more) {
            const int c0n = 2 * (k + 1);
            const float* p = inB + (size_t)c0n * HWin;
            const float* wp2 = w + (size_t)c0n * 9;
#pragma unroll
            for (int r = 0; r < 2; r++)
                if (act[r])
                    __builtin_amdgcn_global_load_lds(
                        (gas_ptr)(p + gOff[r]),
                        (las_ptr)(&sIn[nb][lOff[r]]), 16, 0, 0);
#pragma unroll
            for (int r = 0; r < NW; r++)
                if (wact[r])
                    __builtin_amdgcn_global_load_lds(
                        (gas_ptr)(wp2 + wgo[r]),
                        (las_ptr)(&sW[nb][r * 256 + wvbase]), 4, 0, 0);
        }
        const float* sI = sIn[cur];
        const float* sw = sW[cur];
#pragma unroll
        for (int ci = 0; ci < 2; ci++)
#pragma unroll
            for (int dx = 0; dx < 3; dx++) {
                const float* bp = sI + ci * CI + (2 * ty) * RS + tx + dx;
                float a[4];
#pragma unroll
                for (int j = 0; j < 4; j++) a[j] = bp[j * RS];
#pragma unroll
                for (int dy = 0; dy < 3; dy++) {
                    const float* wp = sw + (ci * 9 + dy * 3 + dx) * COG;
#pragma unroll
                    for (int c = 0; c < COG; c++) {
                        float wv = wp[c];
                        acc[0][c] += a[0 + dy] * wv;
                        acc[1][c] += a[1 + dy] * wv;
                    }
                }
            }
        __syncthreads();
    }

    float* outB = out + (size_t)(b * Cout + cog) * oHp * oWp;
#pragma unroll
    for (int c = 0; c < COG; c++)
#pragma unroll
        for (int j = 0; j < 2; j++)
            outB[(size_t)c * oHp * oWp +
                 (size_t)(tY + 2 * ty + j + oOff) * oWp + tX + tx + oOff] =
                acc[j][c];
    stats_epi<COG>(acc, sRedS, sRedQ, part, cog, slotBase, S, tid);
}

// ---------------------------------------------------------------------------
// bnfin: fp64 combine of per-block partials -> per-channel (scale, shift).
// ---------------------------------------------------------------------------
__global__ void bnfin_k(const double2* __restrict__ part, int S, int C, double invN,
                        const float* __restrict__ g, const float* __restrict__ bb,
                        float2* __restrict__ ss) {
    int c = threadIdx.x;
    if (c >= C) return;
    double sum = 0.0, sq = 0.0;
    for (int s = 0; s < S; s++) {
        double2 p = part[(size_t)c * S + s];
        sum += p.x; sq += p.y;
    }
    double m = sum * invN;
    double v = sq * invN - m * m;
    double sc = (double)g[c] / sqrt(v + 1e-5);
    ss[c] = make_float2((float)sc, (float)((double)bb[c] - m * sc));
}

// ---------------------------------------------------------------------------
// bnact: zero padded border; if ss != nullptr also transform interior with
// lrelu(sc*x+sh) in place. One block per (b,c) plane, C power of two.
// ---------------------------------------------------------------------------
__global__ __launch_bounds__(256) void bnact_k(float* __restrict__ p,
                                               const float2* __restrict__ ss,
                                               int C, int H, int W,
                                               int Hp, int Wp) {
    int pc = blockIdx.x;
    int c = pc & (C - 1);
    float2 t = ss ? ss[c] : make_float2(1.f, 0.f);
    bool xf = (ss != nullptr);
    float* pl = p + (size_t)pc * Hp * Wp;
    int n = Hp * Wp;
    for (int i = threadIdx.x; i < n; i += 256) {
        int y = i / Wp, x = i - y * Wp;
        bool inter = (y >= 1) && (y <= H) && (x >= 1) && (x <= W);
        if (!inter) pl[i] = 0.f;
        else if (xf) { float v = pl[i]; pl[i] = lrelu(t.x * v + t.y); }
    }
}

// ---------------------------------------------------------------------------
// h6 raw (8,256,64,64) + BN6+lrelu -> tok (8,4096,256)
// ---------------------------------------------------------------------------
__global__ __launch_bounds__(256) void transp_k(const float* __restrict__ h6,
                                                const float2* __restrict__ ss,
                                                float* __restrict__ tok) {
    __shared__ float sT[32][33];
    int tx = threadIdx.x & 31, ty = threadIdx.x >> 5;
    int n0 = blockIdx.x * 32, d0 = blockIdx.y * 32, b = blockIdx.z;
    const float* hb = h6 + ((size_t)b * 256 + d0) * 4096 + n0;
#pragma unroll
    for (int r = 0; r < 4; r++) {
        int d = ty + 8 * r;
        float2 t = ss[d0 + d];
        sT[d][tx] = lrelu(t.x * hb[d * 4096 + tx] + t.y);
    }
    __syncthreads();
    float* tb = tok + ((size_t)b * 4096 + n0) * 256 + d0;
#pragma unroll
    for (int r = 0; r < 4; r++) {
        int n = ty + 8 * r;
        tb[n * 256 + tx] = sT[tx][n];
    }
}

// ---------------------------------------------------------------------------
// Token stage: gating argmax, selected-expert body slice, ortho, cls MLP.
// ---------------------------------------------------------------------------
__global__ __launch_bounds__(256) void token_k(const float* __restrict__ tok,
                                               const float* __restrict__ wg,
                                               const float* __restrict__ bw,
                                               const float* __restrict__ bb,
                                               const float* __restrict__ ow,
                                               const float* __restrict__ w1,
                                               const float* __restrict__ b1,
                                               const float* __restrict__ w2,
                                               const float* __restrict__ b2,
                                               float* __restrict__ outp) {
    __shared__ float sf[4][256];
    const int tid = threadIdx.x, wave = tid >> 6, l = tid & 63;
    const int t = blockIdx.x * 4 + wave;
    const float4 tv = reinterpret_cast<const float4*>(tok + (size_t)t * 256)[l];
    sf[wave][4 * l + 0] = tv.x; sf[wave][4 * l + 1] = tv.y;
    sf[wave][4 * l + 2] = tv.z; sf[wave][4 * l + 3] = tv.w;

    float lg[12];
#pragma unroll
    for (int e = 0; e < 12; e++) lg[e] = 0.f;
    const float tj[4] = {tv.x, tv.y, tv.z, tv.w};
#pragma unroll
    for (int j = 0; j < 4; j++) {
        const float* wr = wg + (4 * l + j) * 12;
#pragma unroll
        for (int e = 0; e < 12; e++) lg[e] += tj[j] * wr[e];
    }
#pragma unroll
    for (int off = 32; off > 0; off >>= 1) {
#pragma unroll
        for (int e = 0; e < 12; e++) lg[e] += __shfl_xor(lg[e], off);
    }
    int idx = 0; float best = lg[0];
#pragma unroll
    for (int e = 1; e < 12; e++)
        if (lg[e] > best) { best = lg[e]; idx = e; }
    const int cb = idx * 256;

    float f0 = 0.f, f1 = 0.f, f2 = 0.f, f3 = 0.f;
    const float* bwp = bw + cb + 4 * l;
#pragma unroll 4
    for (int d = 0; d < 256; d++) {
        const float td = sf[wave][d];
        const float4 wv = *reinterpret_cast<const float4*>(bwp + (size_t)d * 3072);
        f0 += td * wv.x; f1 += td * wv.y;
        f2 += td * wv.z; f3 += td * wv.w;
    }
    float fj[4] = {f0, f1, f2, f3};
#pragma unroll
    for (int j = 0; j < 4; j++) {
        int jj = cb + 4 * l + j;
        float v = lrelu(fj[j] + bb[jj]);
        v = lrelu(v * ow[jj]);
        sf[wave][4 * l + j] = v;
    }

    float o = 0.f;
    if (l < 32) {
        float h = b1[l];
#pragma unroll 4
        for (int j = 0; j < 256; j++) h += sf[wave][j] * w1[j * 32 + l];
        h = lrelu(h);
        o = h * w2[l];
    }
    o += __shfl_xor(o, 16); o += __shfl_xor(o, 8); o += __shfl_xor(o, 4);
    o += __shfl_xor(o, 2);  o += __shfl_xor(o, 1);
    if (l == 0) outp[t] = o + b2[0];
}

// ---------------------------------------------------------------------------
extern "C" void kernel_launch(void* const* d_in, const int* in_sizes, int n_in,
                              void* d_out, int out_size, void* d_ws, size_t ws_size,
                              hipStream_t stream) {
    const float* x   = (const float*)d_in[0];
    const float* w0  = (const float*)d_in[1];
    const float* b0  = (const float*)d_in[2];
    const float* w1  = (const float*)d_in[3];
    const float* g1  = (const float*)d_in[4];
    const float* be1 = (const float*)d_in[5];
    const float* w2  = (const float*)d_in[6];
    const float* g2  = (const float*)d_in[7];
    const float* be2 = (const float*)d_in[8];
    const float* w3  = (const float*)d_in[9];
    const float* g3  = (const float*)d_in[10];
    const float* be3 = (const float*)d_in[11];
    const float* w4  = (const float*)d_in[12];
    const float* g4  = (const float*)d_in[13];
    const float* be4 = (const float*)d_in[14];
    const float* w5  = (const float*)d_in[15];
    const float* g5  = (const float*)d_in[16];
    const float* be5 = (const float*)d_in[17];
    const float* w6  = (const float*)d_in[18];
    const float* g6  = (const float*)d_in[19];
    const float* be6 = (const float*)d_in[20];
    const float* wg  = (const float*)d_in[21];
    const float* bw  = (const float*)d_in[22];
    const float* bbp = (const float*)d_in[23];
    const float* owp = (const float*)d_in[24];
    const float* cw1 = (const float*)d_in[25];
    const float* cb1 = (const float*)d_in[26];
    const float* cw2 = (const float*)d_in[27];
    const float* cb2 = (const float*)d_in[28];

    char* W = (char*)d_ws;
    float2* ssb = (float2*)W;                 // ss tables in [0,16K)
    float2* ss1 = ssb;
    float2* ss2 = ssb + 64;
    float2* ss3 = ssb + 192;
    float2* ss4 = ssb + 320;
    float2* ss5 = ssb + 576;
    float2* ss6 = ssb + 832;
    double2* part = (double2*)(W + 16384);    // up to 512 KiB (conv2: 128ch x 256 slots)

    // Big region @540672. Max span = 540672 + 105,431,040 = 105.97 MB
    // (R13 proved 105.71 MB OK, R6 proved 173.6 MB fails).
    char* BIG = W + 540672;
    float* h0p = (float*)(BIG);               // (4,64,258,260) 68.69 MB [0,68.7M)
    float* h1p = (float*)(BIG + 70287360);    // (8,64,130,132) 35.14 MB [70.3M,105.4M)
    float* h2p = (float*)(BIG);               // (8,128,130,132) 70.29 MB [0,70.3M)
    float* h3p = (float*)(BIG + 70287360);    // (8,128,66,68) 18.4 MB (h1p dead)
    float* h4p = (float*)(BIG);               // (8,256,66,68) 36.77 MB (h2p dead)
    float* h5p = (float*)(BIG + 36765696);    // (8,256,66,68) (h3p dead after conv4)
    float* h6  = (float*)(BIG);               // (8,256,64,64) 32 MiB (h4p dead)
    float* tok = (float*)(BIG + 36765696);    // (8,4096,256) 32 MiB (h5p dead)

    // zero h0p borders once (conv0 halves only write interior)
    bnact_k<<<256, 256, 0, stream>>>(h0p, nullptr, 64, 256, 256, 258, 260);
    // conv0 (padded out) + conv1 (async 32x16 tiles, fused stats) per half
    for (int half = 0; half < 2; half++) {
        conv0_k<<<dim3(64, 4, 4), 256, 0, stream>>>(
            x + (size_t)half * 4 * 3 * 65536, w0, b0, h0p);
        c4x4p_k<8><<<dim3(32, 4, 8), 256, 0, stream>>>(
            h0p, w1, h1p + (size_t)half * 4 * 64 * 17160, part, half * 128, 256,
            64, 64, 256, 258, 260, 130, 132, 1);
    }
    bnfin_k<<<1, 256, 0, stream>>>(part, 256, 64, 1.0 / 131072.0, g1, be1, ss1);
    bnact_k<<<512, 256, 0, stream>>>(h1p, ss1, 64, 128, 128, 130, 132);
    // conv2 3x3 async 32x16: h1p -> h2p padded interior, fused stats (S=256)
    c3x3_k<8><<<dim3(32, 8, 16), 256, 0, stream>>>(
        h1p, w2, h2p, part, 0, 256, 64, 128, 128, 130, 132, 130, 132, 1);
    bnfin_k<<<1, 256, 0, stream>>>(part, 256, 128, 1.0 / 131072.0, g2, be2, ss2);
    bnact_k<<<1024, 256, 0, stream>>>(h2p, ss2, 128, 128, 128, 130, 132);
    // conv3 4x4 s2 async 32x16: h2p -> h3p padded interior, fused stats (S=64)
    c4x4p_k<8><<<dim3(8, 8, 16), 256, 0, stream>>>(
        h2p, w3, h3p, part, 0, 64, 128, 128, 128, 130, 132, 66, 68, 1);
    bnfin_k<<<1, 256, 0, stream>>>(part, 64, 128, 1.0 / 32768.0, g3, be3, ss3);
    bnact_k<<<1024, 256, 0, stream>>>(h3p, ss3, 128, 64, 64, 66, 68);
    // conv4 3x3 async 32x16: h3p -> h4p, fused stats
    c3x3_k<8><<<dim3(8, 8, 32), 256, 0, stream>>>(
        h3p, w4, h4p, part, 0, 64, 128, 256, 64, 66, 68, 66, 68, 1);
    bnfin_k<<<1, 256, 0, stream>>>(part, 64, 256, 1.0 / 32768.0, g4, be4, ss4);
    bnact_k<<<2048, 256, 0, stream>>>(h4p, ss4, 256, 64, 64, 66, 68);
    // conv5 3x3 async 32x16: h4p -> h5p, fused stats
    c3x3_k<8><<<dim3(8, 8, 32), 256, 0, stream>>>(
        h4p, w5, h5p, part, 0, 64, 256, 256, 64, 66, 68, 66, 68, 1);
    bnfin_k<<<1, 256, 0, stream>>>(part, 64, 256, 1.0 / 32768.0, g5, be5, ss5);
    bnact_k<<<2048, 256, 0, stream>>>(h5p, ss5, 256, 64, 64, 66, 68);
    // conv6 3x3 async 32x16: h5p -> h6 unpadded, fused stats
    c3x3_k<8><<<dim3(8, 8, 32), 256, 0, stream>>>(
        h5p, w6, h6, part, 0, 64, 256, 256, 64, 66, 68, 64, 64, 0);
    bnfin_k<<<1, 256, 0, stream>>>(part, 64, 256, 1.0 / 32768.0, g6, be6, ss6);
    // transpose + BN6 + lrelu -> tok
    transp_k<<<dim3(128, 8, 8), 256, 0, stream>>>(h6, ss6, tok);
    // token stage -> out fp32 (8,4096,1)
    token_k<<<8192, 256, 0, stream>>>(tok, wg, bw, bbp, owp, cw1, cb1, cw2, cb2,
                                      (float*)d_out);
}

// Round 15
// 2675.335 us; speedup vs baseline: 1.0690x; 1.0690x over previous
//
#include <hip/hip_runtime.h>

__device__ __forceinline__ float lrelu(float x) { return x >= 0.f ? x : 0.2f * x; }

typedef const __attribute__((address_space(1))) void* gas_ptr;
typedef __attribute__((address_space(3))) void* las_ptr;

// ---------------------------------------------------------------------------
// conv0: fp32 x (4,3,256,256) (half batch), w (64,3,3,3), s1 p1, +bias+lrelu
// -> ACTIVATED fp32 PADDED h0p (4,64,258,260), interior at (1,1)
// ---------------------------------------------------------------------------
__global__ __launch_bounds__(256) void conv0_k(const float* __restrict__ x,
                                               const float* __restrict__ w,
                                               const float* __restrict__ bias,
                                               float* __restrict__ out) {
    __shared__ float sIn[3][34][34];
    __shared__ float sW[27][16];
    const int H = 256;
    int tid = threadIdx.x, tx = tid & 31, ty = tid >> 5;
    int tX = (blockIdx.x & 7) * 32, tY = (blockIdx.x >> 3) * 32;
    int b = blockIdx.y, cog = blockIdx.z * 16;
    float acc[4][16] = {};
    const float* inB = x + (size_t)b * 3 * H * H;
    for (int idx = tid; idx < 3 * 1156; idx += 256) {
        int ci = idx / 1156, r = idx % 1156, iy = r / 34, ix = r % 34;
        int gy = tY - 1 + iy, gx = tX - 1 + ix;
        float v = 0.f;
        if ((unsigned)gy < 256u && (unsigned)gx < 256u)
            v = inB[(ci * H + gy) * H + gx];
        sIn[ci][iy][ix] = v;
    }
    for (int idx = tid; idx < 27 * 16; idx += 256) {
        int co = idx & 15, rest = idx >> 4;
        sW[rest][co] = w[(cog + co) * 27 + rest];
    }
    __syncthreads();
#pragma unroll
    for (int ci = 0; ci < 3; ci++)
#pragma unroll
        for (int dy = 0; dy < 3; dy++)
#pragma unroll
            for (int dx = 0; dx < 3; dx++) {
                float a0 = sIn[ci][ty + dy][tx + dx];
                float a1 = sIn[ci][ty + 8 + dy][tx + dx];
                float a2 = sIn[ci][ty + 16 + dy][tx + dx];
                float a3 = sIn[ci][ty + 24 + dy][tx + dx];
                const float* wp = sW[ci * 9 + dy * 3 + dx];
#pragma unroll
                for (int co = 0; co < 16; co++) {
                    float wv = wp[co];
                    acc[0][co] += a0 * wv; acc[1][co] += a1 * wv;
                    acc[2][co] += a2 * wv; acc[3][co] += a3 * wv;
                }
            }
    float* outB = out + (size_t)(b * 64 + cog) * 67080;   // 258*260
#pragma unroll
    for (int co = 0; co < 16; co++) {
        float bv = bias[cog + co];
#pragma unroll
        for (int r = 0; r < 4; r++)
            outB[(size_t)co * 67080 + (size_t)(tY + ty + 8 * r + 1) * 260 +
                 tX + tx + 1] = lrelu(acc[r][co] + bv);
    }
}

// ---------------------------------------------------------------------------
// Wave-shuffle BN-stats epilogue: per-thread NA values -> wave reduce (6
// shfl) -> tiny LDS -> per-channel double2 partial.
// ---------------------------------------------------------------------------
template <int COG, int NA>
__device__ __forceinline__ void stats_epi(float (&acc)[NA][COG],
                                          float* sRedS, float* sRedQ,
                                          double2* part, int cog,
                                          int slotBase, int S, int tid) {
    const int wv = tid >> 6, l = tid & 63;
#pragma unroll
    for (int c = 0; c < COG; c++) {
        float s = 0.f, q = 0.f;
#pragma unroll
        for (int j = 0; j < NA; j++) { float v = acc[j][c]; s += v; q += v * v; }
#pragma unroll
        for (int off = 32; off > 0; off >>= 1) {
            s += __shfl_xor(s, off);
            q += __shfl_xor(q, off);
        }
        if (l == 0) { sRedS[wv * COG + c] = s; sRedQ[wv * COG + c] = q; }
    }
    __syncthreads();
    if (tid < COG) {
        float s = sRedS[tid] + sRedS[COG + tid] + sRedS[2 * COG + tid] +
                  sRedS[3 * COG + tid];
        float q = sRedQ[tid] + sRedQ[COG + tid] + sRedQ[2 * COG + tid] +
                  sRedQ[3 * COG + tid];
        int slot = slotBase + blockIdx.y * gridDim.x + blockIdx.x;
        part[(size_t)(cog + tid) * S + slot].x = (double)s;
        part[(size_t)(cog + tid) * S + slot].y = (double)q;
    }
}

// ---------------------------------------------------------------------------
// Async padded 4x4 s2 conv (conv1, conv3), 32x16-out tiles (2 rows/thread).
// Input ACTIVATED padded (Hp,Wp), interior (1,1), borders zero. Pure
// global_load_lds staging (R11-proven LDS-linear pattern). Fused stats.
// (R14 showed this small-tile variant is neutral-to-positive here: big
// input + small z-fan-out -> no L2 thrash, unlike c3x3.)
// ---------------------------------------------------------------------------
template <int COG>
__global__ __launch_bounds__(256) void c4x4p_k(const float* __restrict__ in,
                                               const float* __restrict__ w,
                                               float* __restrict__ out,
                                               double2* __restrict__ part,
                                               int slotBase, int S,
                                               int Cin, int Cout, int Hin,
                                               int Hp, int Wp,
                                               int oHp, int oWp, int oOff) {
    __shared__ float sIn[2][2312];            // 34 rows x 68 cols
    __shared__ float sW[2][16 * COG];
    __shared__ float sRedS[4 * COG], sRedQ[4 * COG];
    const int Hout = Hin >> 1;
    const int tid = threadIdx.x, tx = tid & 31, ty = tid >> 5;
    const int tpr = Hout >> 5;
    const int tX = (blockIdx.x % tpr) * 32, tY = (blockIdx.x / tpr) * 16;
    const int b = blockIdx.y, cog = blockIdx.z * COG;
    const int HWin = Hp * Wp;
    const float* inB = in + (size_t)b * Cin * HWin;
    const int wvbase = tid & ~63;

    int gOff[3]; int lOff[3]; bool act[3];
#pragma unroll
    for (int r = 0; r < 3; r++) {
        int idx = tid + r * 256;
        bool a = idx < 578;                   // 34 rows x 17 float4
        int row = idx / 17, c4 = idx % 17;
        gOff[r] = a ? ((2 * tY + row) * Wp + 2 * tX + 4 * c4) : 0;
        lOff[r] = (r * 256 + wvbase) * 4;
        act[r] = a;
    }
    const int wco = tid % COG, wt = tid / COG;
    const int wgo = ((cog + wco) * Cin) * 16 + wt;
    const bool wact = tid < 16 * COG;

    float acc[2][COG];
#pragma unroll
    for (int j = 0; j < 2; j++)
#pragma unroll
        for (int c = 0; c < COG; c++) acc[j][c] = 0.f;

#pragma unroll
    for (int r = 0; r < 3; r++)
        if (act[r])
            __builtin_amdgcn_global_load_lds((gas_ptr)(inB + gOff[r]),
                                             (las_ptr)(&sIn[0][lOff[r]]), 16, 0, 0);
    if (wact)
        __builtin_amdgcn_global_load_lds((gas_ptr)(w + wgo),
                                         (las_ptr)(&sW[0][wvbase]), 4, 0, 0);
    __syncthreads();

    for (int k = 0; k < Cin; k++) {
        const int cur = k & 1, nb = cur ^ 1;
        const bool more = (k + 1) < Cin;
        if (more) {
            const float* p = inB + (size_t)(k + 1) * HWin;
#pragma unroll
            for (int r = 0; r < 3; r++)
                if (act[r])
                    __builtin_amdgcn_global_load_lds(
                        (gas_ptr)(p + gOff[r]),
                        (las_ptr)(&sIn[nb][lOff[r]]), 16, 0, 0);
            if (wact)
                __builtin_amdgcn_global_load_lds(
                    (gas_ptr)(w + wgo + (k + 1) * 16),
                    (las_ptr)(&sW[nb][wvbase]), 4, 0, 0);
        }
        const float* sI = sIn[cur];
        const float* sw = sW[cur];
#pragma unroll
        for (int dy = 0; dy < 4; dy++)
#pragma unroll
            for (int dx = 0; dx < 4; dx++) {
                const float* bp = sI + (4 * ty + dy) * 68 + 2 * tx + dx;
                float a0 = bp[0];
                float a1 = bp[2 * 68];
                const float* wp = sw + (dy * 4 + dx) * COG;
#pragma unroll
                for (int c = 0; c < COG; c++) {
                    float wv = wp[c];
                    acc[0][c] += a0 * wv; acc[1][c] += a1 * wv;
                }
            }
        __syncthreads();
    }

    float* outB = out + (size_t)(b * Cout + cog) * oHp * oWp;
#pragma unroll
    for (int c = 0; c < COG; c++)
#pragma unroll
        for (int j = 0; j < 2; j++)
            outB[(size_t)c * oHp * oWp +
                 (size_t)(tY + 2 * ty + j + oOff) * oWp + tX + tx + oOff] =
                acc[j][c];
    stats_epi<COG, 2>(acc, sRedS, sRedQ, part, cog, slotBase, S, tid);
}

// ---------------------------------------------------------------------------
// Async padded 3x3 s1 conv, 32x32-out tiles (R13-proven geometry: 4 rows/
// thread, 6-row register reuse), double-buffered LDS, global_load_lds
// staging, wave-shuffle fused stats. R14 proved 32x16 tiles double HBM
// FETCH (L2 thrash from 2x blocks on small inputs) — keep 32x32.
// ---------------------------------------------------------------------------
template <int COG>
__global__ __launch_bounds__(256) void c3x3_k(const float* __restrict__ in,
                                              const float* __restrict__ w,
                                              float* __restrict__ out,
                                              double2* __restrict__ part,
                                              int slotBase, int S,
                                              int Cin, int Cout, int H,
                                              int Hp, int Wp,
                                              int oHp, int oWp, int oOff) {
    constexpr int RS = 36;
    constexpr int CI = 34 * RS;               // 1224
    __shared__ float sIn[2][2 * CI];
    __shared__ float sW[2][18 * COG];
    __shared__ float sRedS[4 * COG], sRedQ[4 * COG];
    const int tid = threadIdx.x, tx = tid & 31, ty = tid >> 5;
    const int tpr = H >> 5;
    const int tX = (blockIdx.x % tpr) * 32, tY = (blockIdx.x / tpr) * 32;
    const int b = blockIdx.y, cog = blockIdx.z * COG;
    const int HWin = Hp * Wp;
    const float* inB = in + (size_t)b * Cin * HWin;
    const int wvbase = tid & ~63;

    int gOff[3]; int lOff[3]; bool act[3];
#pragma unroll
    for (int r = 0; r < 3; r++) {
        int idx = tid + r * 256;
        bool a = idx < 612;                   // 2 cins x 34 rows x 9 float4
        int ci = idx / 306, rem = idx % 306;
        int row = rem / 9, c4 = rem % 9;
        gOff[r] = a ? (ci * HWin + (tY + row) * Wp + tX + 4 * c4) : 0;
        lOff[r] = (r * 256 + wvbase) * 4;
        act[r] = a;
    }
    constexpr int NW = (18 * COG + 255) / 256;
    int wgo[NW]; bool wact[NW];
#pragma unroll
    for (int r = 0; r < NW; r++) {
        int widx = tid + r * 256;
        bool a = widx < 18 * COG;
        int co = widx % COG, rest = widx / COG;
        int ci = rest / 9, t = rest % 9;
        wgo[r] = a ? (((cog + co) * Cin + ci) * 9 + t) : 0;
        wact[r] = a;
    }

    float acc[4][COG];
#pragma unroll
    for (int j = 0; j < 4; j++)
#pragma unroll
        for (int c = 0; c < COG; c++) acc[j][c] = 0.f;

    const int steps = Cin >> 1;

#pragma unroll
    for (int r = 0; r < 3; r++)
        if (act[r])
            __builtin_amdgcn_global_load_lds(
                (gas_ptr)(inB + gOff[r]),
                (las_ptr)(&sIn[0][lOff[r]]), 16, 0, 0);
#pragma unroll
    for (int r = 0; r < NW; r++)
        if (wact[r])
            __builtin_amdgcn_global_load_lds(
                (gas_ptr)(w + wgo[r]),
                (las_ptr)(&sW[0][r * 256 + wvbase]), 4, 0, 0);
    __syncthreads();

    for (int k = 0; k < steps; k++) {
        const int cur = k & 1;
        const int nb = cur ^ 1;
        const bool more = (k + 1) < steps;
        if (more) {
            const int c0n = 2 * (k + 1);
            const float* p = inB + (size_t)c0n * HWin;
            const float* wp2 = w + (size_t)c0n * 9;
#pragma unroll
            for (int r = 0; r < 3; r++)
                if (act[r])
                    __builtin_amdgcn_global_load_lds(
                        (gas_ptr)(p + gOff[r]),
                        (las_ptr)(&sIn[nb][lOff[r]]), 16, 0, 0);
#pragma unroll
            for (int r = 0; r < NW; r++)
                if (wact[r])
                    __builtin_amdgcn_global_load_lds(
                        (gas_ptr)(wp2 + wgo[r]),
                        (las_ptr)(&sW[nb][r * 256 + wvbase]), 4, 0, 0);
        }
        const float* sI = sIn[cur];
        const float* sw = sW[cur];
#pragma unroll
        for (int ci = 0; ci < 2; ci++)
#pragma unroll
            for (int dx = 0; dx < 3; dx++) {
                const float* bp = sI + ci * CI + (4 * ty) * RS + tx + dx;
                float a[6];
#pragma unroll
                for (int j = 0; j < 6; j++) a[j] = bp[j * RS];
#pragma unroll
                for (int dy = 0; dy < 3; dy++) {
                    const float* wp = sw + (ci * 9 + dy * 3 + dx) * COG;
#pragma unroll
                    for (int c = 0; c < COG; c++) {
                        float wv = wp[c];
                        acc[0][c] += a[0 + dy] * wv;
                        acc[1][c] += a[1 + dy] * wv;
                        acc[2][c] += a[2 + dy] * wv;
                        acc[3][c] += a[3 + dy] * wv;
                    }
                }
            }
        __syncthreads();
    }

    float* outB = out + (size_t)(b * Cout + cog) * oHp * oWp;
#pragma unroll
    for (int c = 0; c < COG; c++)
#pragma unroll
        for (int j = 0; j < 4; j++)
            outB[(size_t)c * oHp * oWp +
                 (size_t)(tY + 4 * ty + j + oOff) * oWp + tX + tx + oOff] =
                acc[j][c];
    stats_epi<COG, 4>(acc, sRedS, sRedQ, part, cog, slotBase, S, tid);
}

// ---------------------------------------------------------------------------
// bnfin: fp64 combine of per-block partials -> per-channel (scale, shift).
// ---------------------------------------------------------------------------
__global__ void bnfin_k(const double2* __restrict__ part, int S, int C, double invN,
                        const float* __restrict__ g, const float* __restrict__ bb,
                        float2* __restrict__ ss) {
    int c = threadIdx.x;
    if (c >= C) return;
    double sum = 0.0, sq = 0.0;
    for (int s = 0; s < S; s++) {
        double2 p = part[(size_t)c * S + s];
        sum += p.x; sq += p.y;
    }
    double m = sum * invN;
    double v = sq * invN - m * m;
    double sc = (double)g[c] / sqrt(v + 1e-5);
    ss[c] = make_float2((float)sc, (float)((double)bb[c] - m * sc));
}

// ---------------------------------------------------------------------------
// bnact: zero padded border; if ss != nullptr also transform interior with
// lrelu(sc*x+sh) in place. One block per (b,c) plane, C power of two.
// ---------------------------------------------------------------------------
__global__ __launch_bounds__(256) void bnact_k(float* __restrict__ p,
                                               const float2* __restrict__ ss,
                                               int C, int H, int W,
                                               int Hp, int Wp) {
    int pc = blockIdx.x;
    int c = pc & (C - 1);
    float2 t = ss ? ss[c] : make_float2(1.f, 0.f);
    bool xf = (ss != nullptr);
    float* pl = p + (size_t)pc * Hp * Wp;
    int n = Hp * Wp;
    for (int i = threadIdx.x; i < n; i += 256) {
        int y = i / Wp, x = i - y * Wp;
        bool inter = (y >= 1) && (y <= H) && (x >= 1) && (x <= W);
        if (!inter) pl[i] = 0.f;
        else if (xf) { float v = pl[i]; pl[i] = lrelu(t.x * v + t.y); }
    }
}

// ---------------------------------------------------------------------------
// h6 raw (8,256,64,64) + BN6+lrelu -> tok (8,4096,256)
// ---------------------------------------------------------------------------
__global__ __launch_bounds__(256) void transp_k(const float* __restrict__ h6,
                                                const float2* __restrict__ ss,
                                                float* __restrict__ tok) {
    __shared__ float sT[32][33];
    int tx = threadIdx.x & 31, ty = threadIdx.x >> 5;
    int n0 = blockIdx.x * 32, d0 = blockIdx.y * 32, b = blockIdx.z;
    const float* hb = h6 + ((size_t)b * 256 + d0) * 4096 + n0;
#pragma unroll
    for (int r = 0; r < 4; r++) {
        int d = ty + 8 * r;
        float2 t = ss[d0 + d];
        sT[d][tx] = lrelu(t.x * hb[d * 4096 + tx] + t.y);
    }
    __syncthreads();
    float* tb = tok + ((size_t)b * 4096 + n0) * 256 + d0;
#pragma unroll
    for (int r = 0; r < 4; r++) {
        int n = ty + 8 * r;
        tb[n * 256 + tx] = sT[tx][n];
    }
}

// ---------------------------------------------------------------------------
// Token stage: gating argmax, selected-expert body slice, ortho, cls MLP.
// ---------------------------------------------------------------------------
__global__ __launch_bounds__(256) void token_k(const float* __restrict__ tok,
                                               const float* __restrict__ wg,
                                               const float* __restrict__ bw,
                                               const float* __restrict__ bb,
                                               const float* __restrict__ ow,
                                               const float* __restrict__ w1,
                                               const float* __restrict__ b1,
                                               const float* __restrict__ w2,
                                               const float* __restrict__ b2,
                                               float* __restrict__ outp) {
    __shared__ float sf[4][256];
    const int tid = threadIdx.x, wave = tid >> 6, l = tid & 63;
    const int t = blockIdx.x * 4 + wave;
    const float4 tv = reinterpret_cast<const float4*>(tok + (size_t)t * 256)[l];
    sf[wave][4 * l + 0] = tv.x; sf[wave][4 * l + 1] = tv.y;
    sf[wave][4 * l + 2] = tv.z; sf[wave][4 * l + 3] = tv.w;

    float lg[12];
#pragma unroll
    for (int e = 0; e < 12; e++) lg[e] = 0.f;
    const float tj[4] = {tv.x, tv.y, tv.z, tv.w};
#pragma unroll
    for (int j = 0; j < 4; j++) {
        const float* wr = wg + (4 * l + j) * 12;
#pragma unroll
        for (int e = 0; e < 12; e++) lg[e] += tj[j] * wr[e];
    }
#pragma unroll
    for (int off = 32; off > 0; off >>= 1) {
#pragma unroll
        for (int e = 0; e < 12; e++) lg[e] += __shfl_xor(lg[e], off);
    }
    int idx = 0; float best = lg[0];
#pragma unroll
    for (int e = 1; e < 12; e++)
        if (lg[e] > best) { best = lg[e]; idx = e; }
    const int cb = idx * 256;

    float f0 = 0.f, f1 = 0.f, f2 = 0.f, f3 = 0.f;
    const float* bwp = bw + cb + 4 * l;
#pragma unroll 4
    for (int d = 0; d < 256; d++) {
        const float td = sf[wave][d];
        const float4 wv = *reinterpret_cast<const float4*>(bwp + (size_t)d * 3072);
        f0 += td * wv.x; f1 += td * wv.y;
        f2 += td * wv.z; f3 += td * wv.w;
    }
    float fj[4] = {f0, f1, f2, f3};
#pragma unroll
    for (int j = 0; j < 4; j++) {
        int jj = cb + 4 * l + j;
        float v = lrelu(fj[j] + bb[jj]);
        v = lrelu(v * ow[jj]);
        sf[wave][4 * l + j] = v;
    }

    float o = 0.f;
    if (l < 32) {
        float h = b1[l];
#pragma unroll 4
        for (int j = 0; j < 256; j++) h += sf[wave][j] * w1[j * 32 + l];
        h = lrelu(h);
        o = h * w2[l];
    }
    o += __shfl_xor(o, 16); o += __shfl_xor(o, 8); o += __shfl_xor(o, 4);
    o += __shfl_xor(o, 2);  o += __shfl_xor(o, 1);
    if (l == 0) outp[t] = o + b2[0];
}

// ---------------------------------------------------------------------------
extern "C" void kernel_launch(void* const* d_in, const int* in_sizes, int n_in,
                              void* d_out, int out_size, void* d_ws, size_t ws_size,
                              hipStream_t stream) {
    const float* x   = (const float*)d_in[0];
    const float* w0  = (const float*)d_in[1];
    const float* b0  = (const float*)d_in[2];
    const float* w1  = (const float*)d_in[3];
    const float* g1  = (const float*)d_in[4];
    const float* be1 = (const float*)d_in[5];
    const float* w2  = (const float*)d_in[6];
    const float* g2  = (const float*)d_in[7];
    const float* be2 = (const float*)d_in[8];
    const float* w3  = (const float*)d_in[9];
    const float* g3  = (const float*)d_in[10];
    const float* be3 = (const float*)d_in[11];
    const float* w4  = (const float*)d_in[12];
    const float* g4  = (const float*)d_in[13];
    const float* be4 = (const float*)d_in[14];
    const float* w5  = (const float*)d_in[15];
    const float* g5  = (const float*)d_in[16];
    const float* be5 = (const float*)d_in[17];
    const float* w6  = (const float*)d_in[18];
    const float* g6  = (const float*)d_in[19];
    const float* be6 = (const float*)d_in[20];
    const float* wg  = (const float*)d_in[21];
    const float* bw  = (const float*)d_in[22];
    const float* bbp = (const float*)d_in[23];
    const float* owp = (const float*)d_in[24];
    const float* cw1 = (const float*)d_in[25];
    const float* cb1 = (const float*)d_in[26];
    const float* cw2 = (const float*)d_in[27];
    const float* cb2 = (const float*)d_in[28];

    char* W = (char*)d_ws;
    float2* ssb = (float2*)W;                 // ss tables in [0,16K)
    float2* ss1 = ssb;
    float2* ss2 = ssb + 64;
    float2* ss3 = ssb + 192;
    float2* ss4 = ssb + 320;
    float2* ss5 = ssb + 576;
    float2* ss6 = ssb + 832;
    double2* part = (double2*)(W + 16384);    // up to 512 KiB

    // Big region @540672. Max span = 105.97 MB (R13/R14-proven).
    char* BIG = W + 540672;
    float* h0p = (float*)(BIG);               // (4,64,258,260) 68.69 MB
    float* h1p = (float*)(BIG + 70287360);    // (8,64,130,132) 35.14 MB
    float* h2p = (float*)(BIG);               // (8,128,130,132) 70.29 MB
    float* h3p = (float*)(BIG + 70287360);    // (8,128,66,68) 18.4 MB
    float* h4p = (float*)(BIG);               // (8,256,66,68) 36.77 MB
    float* h5p = (float*)(BIG + 36765696);    // (8,256,66,68)
    float* h6  = (float*)(BIG);               // (8,256,64,64) 32 MiB
    float* tok = (float*)(BIG + 36765696);    // (8,4096,256) 32 MiB

    // zero h0p borders once (conv0 halves only write interior)
    bnact_k<<<256, 256, 0, stream>>>(h0p, nullptr, 64, 256, 256, 258, 260);
    // conv0 (padded out) + conv1 (async 32x16 tiles, fused stats) per half
    for (int half = 0; half < 2; half++) {
        conv0_k<<<dim3(64, 4, 4), 256, 0, stream>>>(
            x + (size_t)half * 4 * 3 * 65536, w0, b0, h0p);
        c4x4p_k<8><<<dim3(32, 4, 8), 256, 0, stream>>>(
            h0p, w1, h1p + (size_t)half * 4 * 64 * 17160, part, half * 128, 256,
            64, 64, 256, 258, 260, 130, 132, 1);
    }
    bnfin_k<<<1, 256, 0, stream>>>(part, 256, 64, 1.0 / 131072.0, g1, be1, ss1);
    bnact_k<<<512, 256, 0, stream>>>(h1p, ss1, 64, 128, 128, 130, 132);
    // conv2 3x3 async 32x32: h1p -> h2p padded interior, fused stats (S=128)
    c3x3_k<8><<<dim3(16, 8, 16), 256, 0, stream>>>(
        h1p, w2, h2p, part, 0, 128, 64, 128, 128, 130, 132, 130, 132, 1);
    bnfin_k<<<1, 256, 0, stream>>>(part, 128, 128, 1.0 / 131072.0, g2, be2, ss2);
    bnact_k<<<1024, 256, 0, stream>>>(h2p, ss2, 128, 128, 128, 130, 132);
    // conv3 4x4 s2 async 32x16: h2p -> h3p padded interior, fused stats (S=64)
    c4x4p_k<8><<<dim3(8, 8, 16), 256, 0, stream>>>(
        h2p, w3, h3p, part, 0, 64, 128, 128, 128, 130, 132, 66, 68, 1);
    bnfin_k<<<1, 256, 0, stream>>>(part, 64, 128, 1.0 / 32768.0, g3, be3, ss3);
    bnact_k<<<1024, 256, 0, stream>>>(h3p, ss3, 128, 64, 64, 66, 68);
    // conv4 3x3 async 32x32: h3p -> h4p, fused stats (S=32)
    c3x3_k<8><<<dim3(4, 8, 32), 256, 0, stream>>>(
        h3p, w4, h4p, part, 0, 32, 128, 256, 64, 66, 68, 66, 68, 1);
    bnfin_k<<<1, 256, 0, stream>>>(part, 32, 256, 1.0 / 32768.0, g4, be4, ss4);
    bnact_k<<<2048, 256, 0, stream>>>(h4p, ss4, 256, 64, 64, 66, 68);
    // conv5 3x3 async 32x32: h4p -> h5p, fused stats
    c3x3_k<8><<<dim3(4, 8, 32), 256, 0, stream>>>(
        h4p, w5, h5p, part, 0, 32, 256, 256, 64, 66, 68, 66, 68, 1);
    bnfin_k<<<1, 256, 0, stream>>>(part, 32, 256, 1.0 / 32768.0, g5, be5, ss5);
    bnact_k<<<2048, 256, 0, stream>>>(h5p, ss5, 256, 64, 64, 66, 68);
    // conv6 3x3 async 32x32: h5p -> h6 unpadded, fused stats
    c3x3_k<8><<<dim3(4, 8, 32), 256, 0, stream>>>(
        h5p, w6, h6, part, 0, 32, 256, 256, 64, 66, 68, 64, 64, 0);
    bnfin_k<<<1, 256, 0, stream>>>(part, 32, 256, 1.0 / 32768.0, g6, be6, ss6);
    // transpose + BN6 + lrelu -> tok
    transp_k<<<dim3(128, 8, 8), 256, 0, stream>>>(h6, ss6, tok);
    // token stage -> out fp32 (8,4096,1)
    token_k<<<8192, 256, 0, stream>>>(tok, wg, bw, bbp, owp, cw1, cb1, cw2, cb2,
                                      (float*)d_out);
}

// Round 16
// 2637.666 us; speedup vs baseline: 1.0842x; 1.0143x over previous
//
#include <hip/hip_runtime.h>

__device__ __forceinline__ float lrelu(float x) { return x >= 0.f ? x : 0.2f * x; }

typedef const __attribute__((address_space(1))) void* gas_ptr;
typedef __attribute__((address_space(3))) void* las_ptr;

// ---------------------------------------------------------------------------
// conv0: fp32 x (4,3,256,256) (half batch), w (64,3,3,3), s1 p1, +bias+lrelu
// -> ACTIVATED fp32 PADDED h0p (4,64,258,260), interior at (1,1)
// ---------------------------------------------------------------------------
__global__ __launch_bounds__(256) void conv0_k(const float* __restrict__ x,
                                               const float* __restrict__ w,
                                               const float* __restrict__ bias,
                                               float* __restrict__ out) {
    __shared__ float sIn[3][34][34];
    __shared__ float sW[27][16];
    const int H = 256;
    int tid = threadIdx.x, tx = tid & 31, ty = tid >> 5;
    int tX = (blockIdx.x & 7) * 32, tY = (blockIdx.x >> 3) * 32;
    int b = blockIdx.y, cog = blockIdx.z * 16;
    float acc[4][16] = {};
    const float* inB = x + (size_t)b * 3 * H * H;
    for (int idx = tid; idx < 3 * 1156; idx += 256) {
        int ci = idx / 1156, r = idx % 1156, iy = r / 34, ix = r % 34;
        int gy = tY - 1 + iy, gx = tX - 1 + ix;
        float v = 0.f;
        if ((unsigned)gy < 256u && (unsigned)gx < 256u)
            v = inB[(ci * H + gy) * H + gx];
        sIn[ci][iy][ix] = v;
    }
    for (int idx = tid; idx < 27 * 16; idx += 256) {
        int co = idx & 15, rest = idx >> 4;
        sW[rest][co] = w[(cog + co) * 27 + rest];
    }
    __syncthreads();
#pragma unroll
    for (int ci = 0; ci < 3; ci++)
#pragma unroll
        for (int dy = 0; dy < 3; dy++)
#pragma unroll
            for (int dx = 0; dx < 3; dx++) {
                float a0 = sIn[ci][ty + dy][tx + dx];
                float a1 = sIn[ci][ty + 8 + dy][tx + dx];
                float a2 = sIn[ci][ty + 16 + dy][tx + dx];
                float a3 = sIn[ci][ty + 24 + dy][tx + dx];
                const float* wp = sW[ci * 9 + dy * 3 + dx];
#pragma unroll
                for (int co = 0; co < 16; co++) {
                    float wv = wp[co];
                    acc[0][co] += a0 * wv; acc[1][co] += a1 * wv;
                    acc[2][co] += a2 * wv; acc[3][co] += a3 * wv;
                }
            }
    float* outB = out + (size_t)(b * 64 + cog) * 67080;   // 258*260
#pragma unroll
    for (int co = 0; co < 16; co++) {
        float bv = bias[cog + co];
#pragma unroll
        for (int r = 0; r < 4; r++)
            outB[(size_t)co * 67080 + (size_t)(tY + ty + 8 * r + 1) * 260 +
                 tX + tx + 1] = lrelu(acc[r][co] + bv);
    }
}

// ---------------------------------------------------------------------------
// Wave-shuffle BN-stats epilogue: per-thread NA values -> wave reduce (6
// shfl) -> tiny LDS -> per-channel double2 partial.
// ---------------------------------------------------------------------------
template <int COG, int NA>
__device__ __forceinline__ void stats_epi(float (&acc)[NA][COG],
                                          float* sRedS, float* sRedQ,
                                          double2* part, int cog,
                                          int slotBase, int S, int tid) {
    const int wv = tid >> 6, l = tid & 63;
#pragma unroll
    for (int c = 0; c < COG; c++) {
        float s = 0.f, q = 0.f;
#pragma unroll
        for (int j = 0; j < NA; j++) { float v = acc[j][c]; s += v; q += v * v; }
#pragma unroll
        for (int off = 32; off > 0; off >>= 1) {
            s += __shfl_xor(s, off);
            q += __shfl_xor(q, off);
        }
        if (l == 0) { sRedS[wv * COG + c] = s; sRedQ[wv * COG + c] = q; }
    }
    __syncthreads();
    if (tid < COG) {
        float s = sRedS[tid] + sRedS[COG + tid] + sRedS[2 * COG + tid] +
                  sRedS[3 * COG + tid];
        float q = sRedQ[tid] + sRedQ[COG + tid] + sRedQ[2 * COG + tid] +
                  sRedQ[3 * COG + tid];
        int slot = slotBase + blockIdx.y * gridDim.x + blockIdx.x;
        part[(size_t)(cog + tid) * S + slot].x = (double)s;
        part[(size_t)(cog + tid) * S + slot].y = (double)q;
    }
}

// ---------------------------------------------------------------------------
// Async padded 4x4 s2 conv (conv1, conv3), 32x32-out tiles (4 rows/thread —
// R13-proven; R14/R15 proved 32x16 thrashes L2 on conv3). Input ACTIVATED
// padded (Hp,Wp), interior (1,1), borders zero. Pure global_load_lds
// staging (R11-proven LDS-linear pattern). Wave-shuffle fused stats.
// ---------------------------------------------------------------------------
template <int COG>
__global__ __launch_bounds__(256) void c4x4p_k(const float* __restrict__ in,
                                               const float* __restrict__ w,
                                               float* __restrict__ out,
                                               double2* __restrict__ part,
                                               int slotBase, int S,
                                               int Cin, int Cout, int Hin,
                                               int Hp, int Wp,
                                               int oHp, int oWp, int oOff) {
    __shared__ float sIn[2][4488];            // 66 rows x 68 cols
    __shared__ float sW[2][16 * COG];
    __shared__ float sRedS[4 * COG], sRedQ[4 * COG];
    const int Hout = Hin >> 1;
    const int tid = threadIdx.x, tx = tid & 31, ty = tid >> 5;
    const int tpr = Hout >> 5;
    const int tX = (blockIdx.x % tpr) * 32, tY = (blockIdx.x / tpr) * 32;
    const int b = blockIdx.y, cog = blockIdx.z * COG;
    const int HWin = Hp * Wp;
    const float* inB = in + (size_t)b * Cin * HWin;
    const int wvbase = tid & ~63;

    int gOff[5]; int lOff[5]; bool act[5];
#pragma unroll
    for (int r = 0; r < 5; r++) {
        int idx = tid + r * 256;
        bool a = idx < 1122;                  // 66 rows x 17 float4
        int row = idx / 17, c4 = idx % 17;
        gOff[r] = a ? ((2 * tY + row) * Wp + 2 * tX + 4 * c4) : 0;
        lOff[r] = (r * 256 + wvbase) * 4;
        act[r] = a;
    }
    const int wco = tid % COG, wt = tid / COG;
    const int wgo = ((cog + wco) * Cin) * 16 + wt;
    const bool wact = tid < 16 * COG;

    float acc[4][COG];
#pragma unroll
    for (int j = 0; j < 4; j++)
#pragma unroll
        for (int c = 0; c < COG; c++) acc[j][c] = 0.f;

#pragma unroll
    for (int r = 0; r < 5; r++)
        if (act[r])
            __builtin_amdgcn_global_load_lds((gas_ptr)(inB + gOff[r]),
                                             (las_ptr)(&sIn[0][lOff[r]]), 16, 0, 0);
    if (wact)
        __builtin_amdgcn_global_load_lds((gas_ptr)(w + wgo),
                                         (las_ptr)(&sW[0][wvbase]), 4, 0, 0);
    __syncthreads();

    for (int k = 0; k < Cin; k++) {
        const int cur = k & 1, nb = cur ^ 1;
        const bool more = (k + 1) < Cin;
        if (more) {
            const float* p = inB + (size_t)(k + 1) * HWin;
#pragma unroll
            for (int r = 0; r < 5; r++)
                if (act[r])
                    __builtin_amdgcn_global_load_lds(
                        (gas_ptr)(p + gOff[r]),
                        (las_ptr)(&sIn[nb][lOff[r]]), 16, 0, 0);
            if (wact)
                __builtin_amdgcn_global_load_lds(
                    (gas_ptr)(w + wgo + (k + 1) * 16),
                    (las_ptr)(&sW[nb][wvbase]), 4, 0, 0);
        }
        const float* sI = sIn[cur];
        const float* sw = sW[cur];
#pragma unroll
        for (int dy = 0; dy < 4; dy++)
#pragma unroll
            for (int dx = 0; dx < 4; dx++) {
                const float* bp = sI + (2 * ty + dy) * 68 + 2 * tx + dx;
                float a0 = bp[0];
                float a1 = bp[16 * 68];
                float a2 = bp[32 * 68];
                float a3 = bp[48 * 68];
                const float* wp = sw + (dy * 4 + dx) * COG;
#pragma unroll
                for (int c = 0; c < COG; c++) {
                    float wv = wp[c];
                    acc[0][c] += a0 * wv; acc[1][c] += a1 * wv;
                    acc[2][c] += a2 * wv; acc[3][c] += a3 * wv;
                }
            }
        __syncthreads();
    }

    float* outB = out + (size_t)(b * Cout + cog) * oHp * oWp;
#pragma unroll
    for (int c = 0; c < COG; c++)
#pragma unroll
        for (int r = 0; r < 4; r++)
            outB[(size_t)c * oHp * oWp +
                 (size_t)(tY + ty + 8 * r + oOff) * oWp + tX + tx + oOff] =
                acc[r][c];
    stats_epi<COG, 4>(acc, sRedS, sRedQ, part, cog, slotBase, S, tid);
}

// ---------------------------------------------------------------------------
// Async padded 3x3 s1 conv, 32x32-out tiles (R13-proven geometry: 4 rows/
// thread, 6-row register reuse), double-buffered LDS, global_load_lds
// staging, wave-shuffle fused stats. R14 proved 32x16 tiles double HBM
// FETCH (L2 thrash from 2x blocks on small inputs) — keep 32x32.
// ---------------------------------------------------------------------------
template <int COG>
__global__ __launch_bounds__(256) void c3x3_k(const float* __restrict__ in,
                                              const float* __restrict__ w,
                                              float* __restrict__ out,
                                              double2* __restrict__ part,
                                              int slotBase, int S,
                                              int Cin, int Cout, int H,
                                              int Hp, int Wp,
                                              int oHp, int oWp, int oOff) {
    constexpr int RS = 36;
    constexpr int CI = 34 * RS;               // 1224
    __shared__ float sIn[2][2 * CI];
    __shared__ float sW[2][18 * COG];
    __shared__ float sRedS[4 * COG], sRedQ[4 * COG];
    const int tid = threadIdx.x, tx = tid & 31, ty = tid >> 5;
    const int tpr = H >> 5;
    const int tX = (blockIdx.x % tpr) * 32, tY = (blockIdx.x / tpr) * 32;
    const int b = blockIdx.y, cog = blockIdx.z * COG;
    const int HWin = Hp * Wp;
    const float* inB = in + (size_t)b * Cin * HWin;
    const int wvbase = tid & ~63;

    int gOff[3]; int lOff[3]; bool act[3];
#pragma unroll
    for (int r = 0; r < 3; r++) {
        int idx = tid + r * 256;
        bool a = idx < 612;                   // 2 cins x 34 rows x 9 float4
        int ci = idx / 306, rem = idx % 306;
        int row = rem / 9, c4 = rem % 9;
        gOff[r] = a ? (ci * HWin + (tY + row) * Wp + tX + 4 * c4) : 0;
        lOff[r] = (r * 256 + wvbase) * 4;
        act[r] = a;
    }
    constexpr int NW = (18 * COG + 255) / 256;
    int wgo[NW]; bool wact[NW];
#pragma unroll
    for (int r = 0; r < NW; r++) {
        int widx = tid + r * 256;
        bool a = widx < 18 * COG;
        int co = widx % COG, rest = widx / COG;
        int ci = rest / 9, t = rest % 9;
        wgo[r] = a ? (((cog + co) * Cin + ci) * 9 + t) : 0;
        wact[r] = a;
    }

    float acc[4][COG];
#pragma unroll
    for (int j = 0; j < 4; j++)
#pragma unroll
        for (int c = 0; c < COG; c++) acc[j][c] = 0.f;

    const int steps = Cin >> 1;

#pragma unroll
    for (int r = 0; r < 3; r++)
        if (act[r])
            __builtin_amdgcn_global_load_lds(
                (gas_ptr)(inB + gOff[r]),
                (las_ptr)(&sIn[0][lOff[r]]), 16, 0, 0);
#pragma unroll
    for (int r = 0; r < NW; r++)
        if (wact[r])
            __builtin_amdgcn_global_load_lds(
                (gas_ptr)(w + wgo[r]),
                (las_ptr)(&sW[0][r * 256 + wvbase]), 4, 0, 0);
    __syncthreads();

    for (int k = 0; k < steps; k++) {
        const int cur = k & 1;
        const int nb = cur ^ 1;
        const bool more = (k + 1) < steps;
        if (more) {
            const int c0n = 2 * (k + 1);
            const float* p = inB + (size_t)c0n * HWin;
            const float* wp2 = w + (size_t)c0n * 9;
#pragma unroll
            for (int r = 0; r < 3; r++)
                if (act[r])
                    __builtin_amdgcn_global_load_lds(
                        (gas_ptr)(p + gOff[r]),
                        (las_ptr)(&sIn[nb][lOff[r]]), 16, 0, 0);
#pragma unroll
            for (int r = 0; r < NW; r++)
                if (wact[r])
                    __builtin_amdgcn_global_load_lds(
                        (gas_ptr)(wp2 + wgo[r]),
                        (las_ptr)(&sW[nb][r * 256 + wvbase]), 4, 0, 0);
        }
        const float* sI = sIn[cur];
        const float* sw = sW[cur];
#pragma unroll
        for (int ci = 0; ci < 2; ci++)
#pragma unroll
            for (int dx = 0; dx < 3; dx++) {
                const float* bp = sI + ci * CI + (4 * ty) * RS + tx + dx;
                float a[6];
#pragma unroll
                for (int j = 0; j < 6; j++) a[j] = bp[j * RS];
#pragma unroll
                for (int dy = 0; dy < 3; dy++) {
                    const float* wp = sw + (ci * 9 + dy * 3 + dx) * COG;
#pragma unroll
                    for (int c = 0; c < COG; c++) {
                        float wv = wp[c];
                        acc[0][c] += a[0 + dy] * wv;
                        acc[1][c] += a[1 + dy] * wv;
                        acc[2][c] += a[2 + dy] * wv;
                        acc[3][c] += a[3 + dy] * wv;
                    }
                }
            }
        __syncthreads();
    }

    float* outB = out + (size_t)(b * Cout + cog) * oHp * oWp;
#pragma unroll
    for (int c = 0; c < COG; c++)
#pragma unroll
        for (int j = 0; j < 4; j++)
            outB[(size_t)c * oHp * oWp +
                 (size_t)(tY + 4 * ty + j + oOff) * oWp + tX + tx + oOff] =
                acc[j][c];
    stats_epi<COG, 4>(acc, sRedS, sRedQ, part, cog, slotBase, S, tid);
}

// ---------------------------------------------------------------------------
// bnfin: fp64 combine of per-block partials -> per-channel (scale, shift).
// ---------------------------------------------------------------------------
__global__ void bnfin_k(const double2* __restrict__ part, int S, int C, double invN,
                        const float* __restrict__ g, const float* __restrict__ bb,
                        float2* __restrict__ ss) {
    int c = threadIdx.x;
    if (c >= C) return;
    double sum = 0.0, sq = 0.0;
    for (int s = 0; s < S; s++) {
        double2 p = part[(size_t)c * S + s];
        sum += p.x; sq += p.y;
    }
    double m = sum * invN;
    double v = sq * invN - m * m;
    double sc = (double)g[c] / sqrt(v + 1e-5);
    ss[c] = make_float2((float)sc, (float)((double)bb[c] - m * sc));
}

// ---------------------------------------------------------------------------
// bnact: zero padded border; if ss != nullptr also transform interior with
// lrelu(sc*x+sh) in place. One block per (b,c) plane, C power of two.
// ---------------------------------------------------------------------------
__global__ __launch_bounds__(256) void bnact_k(float* __restrict__ p,
                                               const float2* __restrict__ ss,
                                               int C, int H, int W,
                                               int Hp, int Wp) {
    int pc = blockIdx.x;
    int c = pc & (C - 1);
    float2 t = ss ? ss[c] : make_float2(1.f, 0.f);
    bool xf = (ss != nullptr);
    float* pl = p + (size_t)pc * Hp * Wp;
    int n = Hp * Wp;
    for (int i = threadIdx.x; i < n; i += 256) {
        int y = i / Wp, x = i - y * Wp;
        bool inter = (y >= 1) && (y <= H) && (x >= 1) && (x <= W);
        if (!inter) pl[i] = 0.f;
        else if (xf) { float v = pl[i]; pl[i] = lrelu(t.x * v + t.y); }
    }
}

// ---------------------------------------------------------------------------
// h6 raw (8,256,64,64) + BN6+lrelu -> tok (8,4096,256)
// ---------------------------------------------------------------------------
__global__ __launch_bounds__(256) void transp_k(const float* __restrict__ h6,
                                                const float2* __restrict__ ss,
                                                float* __restrict__ tok) {
    __shared__ float sT[32][33];
    int tx = threadIdx.x & 31, ty = threadIdx.x >> 5;
    int n0 = blockIdx.x * 32, d0 = blockIdx.y * 32, b = blockIdx.z;
    const float* hb = h6 + ((size_t)b * 256 + d0) * 4096 + n0;
#pragma unroll
    for (int r = 0; r < 4; r++) {
        int d = ty + 8 * r;
        float2 t = ss[d0 + d];
        sT[d][tx] = lrelu(t.x * hb[d * 4096 + tx] + t.y);
    }
    __syncthreads();
    float* tb = tok + ((size_t)b * 4096 + n0) * 256 + d0;
#pragma unroll
    for (int r = 0; r < 4; r++) {
        int n = ty + 8 * r;
        tb[n * 256 + tx] = sT[tx][n];
    }
}

// ---------------------------------------------------------------------------
// Token stage: gating argmax, selected-expert body slice, ortho, cls MLP.
// ---------------------------------------------------------------------------
__global__ __launch_bounds__(256) void token_k(const float* __restrict__ tok,
                                               const float* __restrict__ wg,
                                               const float* __restrict__ bw,
                                               const float* __restrict__ bb,
                                               const float* __restrict__ ow,
                                               const float* __restrict__ w1,
                                               const float* __restrict__ b1,
                                               const float* __restrict__ w2,
                                               const float* __restrict__ b2,
                                               float* __restrict__ outp) {
    __shared__ float sf[4][256];
    const int tid = threadIdx.x, wave = tid >> 6, l = tid & 63;
    const int t = blockIdx.x * 4 + wave;
    const float4 tv = reinterpret_cast<const float4*>(tok + (size_t)t * 256)[l];
    sf[wave][4 * l + 0] = tv.x; sf[wave][4 * l + 1] = tv.y;
    sf[wave][4 * l + 2] = tv.z; sf[wave][4 * l + 3] = tv.w;

    float lg[12];
#pragma unroll
    for (int e = 0; e < 12; e++) lg[e] = 0.f;
    const float tj[4] = {tv.x, tv.y, tv.z, tv.w};
#pragma unroll
    for (int j = 0; j < 4; j++) {
        const float* wr = wg + (4 * l + j) * 12;
#pragma unroll
        for (int e = 0; e < 12; e++) lg[e] += tj[j] * wr[e];
    }
#pragma unroll
    for (int off = 32; off > 0; off >>= 1) {
#pragma unroll
        for (int e = 0; e < 12; e++) lg[e] += __shfl_xor(lg[e], off);
    }
    int idx = 0; float best = lg[0];
#pragma unroll
    for (int e = 1; e < 12; e++)
        if (lg[e] > best) { best = lg[e]; idx = e; }
    const int cb = idx * 256;

    float f0 = 0.f, f1 = 0.f, f2 = 0.f, f3 = 0.f;
    const float* bwp = bw + cb + 4 * l;
#pragma unroll 4
    for (int d = 0; d < 256; d++) {
        const float td = sf[wave][d];
        const float4 wv = *reinterpret_cast<const float4*>(bwp + (size_t)d * 3072);
        f0 += td * wv.x; f1 += td * wv.y;
        f2 += td * wv.z; f3 += td * wv.w;
    }
    float fj[4] = {f0, f1, f2, f3};
#pragma unroll
    for (int j = 0; j < 4; j++) {
        int jj = cb + 4 * l + j;
        float v = lrelu(fj[j] + bb[jj]);
        v = lrelu(v * ow[jj]);
        sf[wave][4 * l + j] = v;
    }

    float o = 0.f;
    if (l < 32) {
        float h = b1[l];
#pragma unroll 4
        for (int j = 0; j < 256; j++) h += sf[wave][j] * w1[j * 32 + l];
        h = lrelu(h);
        o = h * w2[l];
    }
    o += __shfl_xor(o, 16); o += __shfl_xor(o, 8); o += __shfl_xor(o, 4);
    o += __shfl_xor(o, 2);  o += __shfl_xor(o, 1);
    if (l == 0) outp[t] = o + b2[0];
}

// ---------------------------------------------------------------------------
extern "C" void kernel_launch(void* const* d_in, const int* in_sizes, int n_in,
                              void* d_out, int out_size, void* d_ws, size_t ws_size,
                              hipStream_t stream) {
    const float* x   = (const float*)d_in[0];
    const float* w0  = (const float*)d_in[1];
    const float* b0  = (const float*)d_in[2];
    const float* w1  = (const float*)d_in[3];
    const float* g1  = (const float*)d_in[4];
    const float* be1 = (const float*)d_in[5];
    const float* w2  = (const float*)d_in[6];
    const float* g2  = (const float*)d_in[7];
    const float* be2 = (const float*)d_in[8];
    const float* w3  = (const float*)d_in[9];
    const float* g3  = (const float*)d_in[10];
    const float* be3 = (const float*)d_in[11];
    const float* w4  = (const float*)d_in[12];
    const float* g4  = (const float*)d_in[13];
    const float* be4 = (const float*)d_in[14];
    const float* w5  = (const float*)d_in[15];
    const float* g5  = (const float*)d_in[16];
    const float* be5 = (const float*)d_in[17];
    const float* w6  = (const float*)d_in[18];
    const float* g6  = (const float*)d_in[19];
    const float* be6 = (const float*)d_in[20];
    const float* wg  = (const float*)d_in[21];
    const float* bw  = (const float*)d_in[22];
    const float* bbp = (const float*)d_in[23];
    const float* owp = (const float*)d_in[24];
    const float* cw1 = (const float*)d_in[25];
    const float* cb1 = (const float*)d_in[26];
    const float* cw2 = (const float*)d_in[27];
    const float* cb2 = (const float*)d_in[28];

    char* W = (char*)d_ws;
    float2* ssb = (float2*)W;                 // ss tables in [0,16K)
    float2* ss1 = ssb;
    float2* ss2 = ssb + 64;
    float2* ss3 = ssb + 192;
    float2* ss4 = ssb + 320;
    float2* ss5 = ssb + 576;
    float2* ss6 = ssb + 832;
    double2* part = (double2*)(W + 16384);    // up to 256 KiB (128ch x 128 slots)

    // Big region @540672. Max span = 105.97 MB (R13/R15-proven).
    char* BIG = W + 540672;
    float* h0p = (float*)(BIG);               // (4,64,258,260) 68.69 MB
    float* h1p = (float*)(BIG + 70287360);    // (8,64,130,132) 35.14 MB
    float* h2p = (float*)(BIG);               // (8,128,130,132) 70.29 MB
    float* h3p = (float*)(BIG + 70287360);    // (8,128,66,68) 18.4 MB
    float* h4p = (float*)(BIG);               // (8,256,66,68) 36.77 MB
    float* h5p = (float*)(BIG + 36765696);    // (8,256,66,68)
    float* h6  = (float*)(BIG);               // (8,256,64,64) 32 MiB
    float* tok = (float*)(BIG + 36765696);    // (8,4096,256) 32 MiB

    // zero h0p borders once (conv0 halves only write interior)
    bnact_k<<<256, 256, 0, stream>>>(h0p, nullptr, 64, 256, 256, 258, 260);
    // conv0 (padded out) + conv1 (async 32x32 tiles, fused stats) per half
    for (int half = 0; half < 2; half++) {
        conv0_k<<<dim3(64, 4, 4), 256, 0, stream>>>(
            x + (size_t)half * 4 * 3 * 65536, w0, b0, h0p);
        c4x4p_k<8><<<dim3(16, 4, 8), 256, 0, stream>>>(
            h0p, w1, h1p + (size_t)half * 4 * 64 * 17160, part, half * 64, 128,
            64, 64, 256, 258, 260, 130, 132, 1);
    }
    bnfin_k<<<1, 256, 0, stream>>>(part, 128, 64, 1.0 / 131072.0, g1, be1, ss1);
    bnact_k<<<512, 256, 0, stream>>>(h1p, ss1, 64, 128, 128, 130, 132);
    // conv2 3x3 async 32x32: h1p -> h2p padded interior, fused stats (S=128)
    c3x3_k<8><<<dim3(16, 8, 16), 256, 0, stream>>>(
        h1p, w2, h2p, part, 0, 128, 64, 128, 128, 130, 132, 130, 132, 1);
    bnfin_k<<<1, 256, 0, stream>>>(part, 128, 128, 1.0 / 131072.0, g2, be2, ss2);
    bnact_k<<<1024, 256, 0, stream>>>(h2p, ss2, 128, 128, 128, 130, 132);
    // conv3 4x4 s2 async 32x32: h2p -> h3p padded interior, fused stats (S=32)
    c4x4p_k<8><<<dim3(4, 8, 16), 256, 0, stream>>>(
        h2p, w3, h3p, part, 0, 32, 128, 128, 128, 130, 132, 66, 68, 1);
    bnfin_k<<<1, 256, 0, stream>>>(part, 32, 128, 1.0 / 32768.0, g3, be3, ss3);
    bnact_k<<<1024, 256, 0, stream>>>(h3p, ss3, 128, 64, 64, 66, 68);
    // conv4 3x3 async 32x32: h3p -> h4p, fused stats (S=32)
    c3x3_k<8><<<dim3(4, 8, 32), 256, 0, stream>>>(
        h3p, w4, h4p, part, 0, 32, 128, 256, 64, 66, 68, 66, 68, 1);
    bnfin_k<<<1, 256, 0, stream>>>(part, 32, 256, 1.0 / 32768.0, g4, be4, ss4);
    bnact_k<<<2048, 256, 0, stream>>>(h4p, ss4, 256, 64, 64, 66, 68);
    // conv5 3x3 async 32x32: h4p -> h5p, fused stats
    c3x3_k<8><<<dim3(4, 8, 32), 256, 0, stream>>>(
        h4p, w5, h5p, part, 0, 32, 256, 256, 64, 66, 68, 66, 68, 1);
    bnfin_k<<<1, 256, 0, stream>>>(part, 32, 256, 1.0 / 32768.0, g5, be5, ss5);
    bnact_k<<<2048, 256, 0, stream>>>(h5p, ss5, 256, 64, 64, 66, 68);
    // conv6 3x3 async 32x32: h5p -> h6 unpadded, fused stats
    c3x3_k<8><<<dim3(4, 8, 32), 256, 0, stream>>>(
        h5p, w6, h6, part, 0, 32, 256, 256, 64, 66, 68, 64, 64, 0);
    bnfin_k<<<1, 256, 0, stream>>>(part, 32, 256, 1.0 / 32768.0, g6, be6, ss6);
    // transpose + BN6 + lrelu -> tok
    transp_k<<<dim3(128, 8, 8), 256, 0, stream>>>(h6, ss6, tok);
    // token stage -> out fp32 (8,4096,1)
    token_k<<<8192, 256, 0, stream>>>(tok, wg, bw, bbp, owp, cw1, cb1, cw2, cb2,
                                      (float*)d_out);
}